// Round 9
// baseline (198.522 us; speedup 1.0000x reference)
//
#include <hip/hip_runtime.h>
#include <cstdint>
#include <cstddef>

// B=32 batch, K=4096 complex input pixels, N=4096 complex outputs.
// out[b,n] = sum_k (e_in[b,k]*ts[k]) * w[k,n]   (complex)
// Real-GEMM formulation, K'=8192 interleaved (re,im):
//   A[b][2k]=m_re, A[b][2k+1]=m_im
//   B_re[2k][n]=w_re, B_re[2k+1][n]=-w_im  -> out_re
//   B_im[2k][n]=w_im, B_im[2k+1][n]= w_re  -> out_im
// OUTPUT (established R5): float32 PLANAR — [re-plane 131072][im-plane 131072].
//
// R14: NO split-K partials. Ledger: delivered-BW cap ~2.8-3.1 TB/s falsified
// against every within-gemm lever (R5-R11); dispatch-count theory dead
// (R10/R13: ~2us/dispatch); workspace POISON is timed (~0.35us/MB; R7/R11
// vs R9/R13 totals). So: remove the 32 MB partial round-trip, the reduce
// dispatch, and 16 MB of workspace. Grid = 128 n-strips x 4 k-quarters;
// waves split K 8-way within a block (barrier-free TLP, 16 waves/CU);
// LDS atomic reduce (8 KB) then global f32 atomicAdd into out, which prep
// zeroes (out re-zeroed every invocation -> graph-replay safe; atomic
// order variance irrelevant at absmax tol 1.0; no cross-block ordering).
// A-fragments come from wsA (512 KB -> L2-resident on every XCD).
#define KC 4096
#define NN 4096
#define NB 32
#define HALF (NB * NN)
#define KH 4                 // k-quarters (blockIdx.y)

typedef __attribute__((ext_vector_type(8))) short  bf16x8;  // 8 bf16 (4 VGPRs)
typedef __attribute__((ext_vector_type(16))) float f32x16;  // 32x32 MFMA acc

__device__ __forceinline__ unsigned short f2bf(float f) {
    union { float f; unsigned u; } v; v.f = f;
    unsigned r = v.u + 0x7fffu + ((v.u >> 16) & 1u);
    return (unsigned short)(r >> 16);
}

// ---------------------------------------------------------------------------
// Kernel 1: prep (R9-proven body) + zero out.
// modulated[b,k] = e_in[b,k] * (sigmoid(amp[k]) * exp(i*phase[k]))
// bf16 pairs in MFMA-A octet order: k'=2k+(re:0/im:1), octet o=k'>>3 (=k>>2),
// slot r=k'&7; dword index = ((k>>2)*32 + b)*4 + (k&3), re lo16 / im hi16.
// Each of the 131072 threads also zeroes one float2 of out (1 MB total).
// ---------------------------------------------------------------------------
__global__ __launch_bounds__(256) void prep_kernel(
    const float* __restrict__ in_re, const float* __restrict__ in_im,
    const float* __restrict__ amp,   const float* __restrict__ phase,
    uint32_t* __restrict__ wsA, float* __restrict__ out)
{
    int tid = blockIdx.x * 256 + threadIdx.x;   // 32*4096 threads
    int b = tid >> 12;
    int k = tid & (KC - 1);
    float er = in_re[tid], ei = in_im[tid];
    float a = amp[k], p = phase[k];
    float s = 1.0f / (1.0f + __expf(-a));
    float sn = __sinf(p);
    float cs = __cosf(p);
    float tr = s * cs, ti = s * sn;
    float mr = er * tr - ei * ti;
    float mi = er * ti + ei * tr;
    uint32_t pk = (uint32_t)f2bf(mr) | ((uint32_t)f2bf(mi) << 16);
    wsA[((((k >> 2) << 5) + b) << 2) | (k & 3)] = pk;

    // zero the 262144-float output (2 floats per thread)
    ((float2*)out)[tid] = make_float2(0.f, 0.f);
}

// ---------------------------------------------------------------------------
// Kernel 2: direct-output GEMM. Grid (128 n-strips, 4 k-quarters) x 512.
// Wave w owns complex-k range [kh*1024 + w*128, +128) for the block's 32
// n-cols: 16 steps x {1 A-frag dwordx4 (wsA, L2-hot) + 8 scalar W dwords
// + 2 MFMA} -- R5's numerics-proven inner loop, barrier-free (pure TLP,
// 16 waves/CU). Epilogue: 8-way wave reduce via LDS atomicAdd (free 2-way
// bank aliasing), then global atomicAdd f32 into planar out.
// ---------------------------------------------------------------------------
__global__ __launch_bounds__(512, 4) void gemm_direct(
    const float* __restrict__ w_re, const float* __restrict__ w_im,
    const bf16x8* __restrict__ wsA, float* __restrict__ out)
{
    __shared__ float accS[2][32][32];   // [re/im][b][n]  8 KB

    const int tid   = threadIdx.x;
    const int lane  = tid & 63;
    const int wave  = tid >> 6;          // 0..7
    const int h     = lane >> 5;         // K'-octet half
    const int l32   = lane & 31;
    const int strip = blockIdx.x;        // 0..127 (32-col n-strip)
    const int kh    = blockIdx.y;        // 0..3   (k-quarter)
    const int n     = strip * 32 + l32;
    const int kbase = kh * (KC / KH) + wave * 128;   // this wave's k-range
    const int steps = 128 / 8;                       // 16

    f32x16 accR = {};
    f32x16 accI = {};

    // A: octet index (kbase>>2) + 2t + h, 32 batch-entries of 16 B each.
    const bf16x8* aptr = wsA + ((size_t)(kbase >> 2) + h) * 32 + l32;
    // W: step t covers rows kbase+8t..+7; h-half loads rows +h*4..+h*4+3.
    const float* pre = w_re + (size_t)(kbase + h * 4) * NN + n;
    const float* pim = w_im + (size_t)(kbase + h * 4) * NN + n;

#pragma unroll 4
    for (int t = 0; t < steps; ++t) {
        bf16x8 afrag = aptr[(size_t)(2 * t) * 32];
        const float* pr = pre + (size_t)t * 8 * NN;
        const float* pi = pim + (size_t)t * 8 * NN;
        float r0 = pr[0], r1 = pr[NN], r2 = pr[2 * NN], r3 = pr[3 * NN];
        float i0 = pi[0], i1 = pi[NN], i2 = pi[2 * NN], i3 = pi[3 * NN];

        // f2bf(-x) == f2bf(x)^0x8000 exactly (RNE is sign-symmetric).
        unsigned short br0 = f2bf(r0), br1 = f2bf(r1), br2 = f2bf(r2), br3 = f2bf(r3);
        unsigned short bi0 = f2bf(i0), bi1 = f2bf(i1), bi2 = f2bf(i2), bi3 = f2bf(i3);
        bf16x8 bR, bI;
        bR[0] = (short)br0;  bR[1] = (short)(bi0 ^ 0x8000);
        bR[2] = (short)br1;  bR[3] = (short)(bi1 ^ 0x8000);
        bR[4] = (short)br2;  bR[5] = (short)(bi2 ^ 0x8000);
        bR[6] = (short)br3;  bR[7] = (short)(bi3 ^ 0x8000);
        bI[0] = (short)bi0;  bI[1] = (short)br0;
        bI[2] = (short)bi1;  bI[3] = (short)br1;
        bI[4] = (short)bi2;  bI[5] = (short)br2;
        bI[6] = (short)bi3;  bI[7] = (short)br3;

        accR = __builtin_amdgcn_mfma_f32_32x32x16_bf16(afrag, bR, accR, 0, 0, 0);
        accI = __builtin_amdgcn_mfma_f32_32x32x16_bf16(afrag, bI, accI, 0, 0, 0);
    }

    // ---- 8-way wave reduction in LDS ----------------------------------
    {
        float* af = &accS[0][0][0];     // 2048 floats; 4 per thread
        af[tid] = 0.f; af[tid + 512] = 0.f;
        af[tid + 1024] = 0.f; af[tid + 1536] = 0.f;
    }
    __syncthreads();
    // C/D layout (32x32, verified m74/m101): col = lane&31 (=n),
    // row(batch) = (reg&3) + 8*(reg>>2) + 4*h
#pragma unroll
    for (int r = 0; r < 16; ++r) {
        int brow = (r & 3) + 8 * (r >> 2) + 4 * h;
        atomicAdd(&accS[0][brow][l32], accR[r]);
        atomicAdd(&accS[1][brow][l32], accI[r]);
    }
    __syncthreads();

    // ---- global accumulate: 1024 complex / 512 threads = 2 cols each ---
    {
        const int row = tid >> 4;          // batch 0..31
        const int c0  = (tid & 15) * 2;    // col pair
        const int nb  = strip * 32;
        atomicAdd(&out[row * NN + nb + c0],            accS[0][row][c0]);
        atomicAdd(&out[row * NN + nb + c0 + 1],        accS[0][row][c0 + 1]);
        atomicAdd(&out[HALF + row * NN + nb + c0],     accS[1][row][c0]);
        atomicAdd(&out[HALF + row * NN + nb + c0 + 1], accS[1][row][c0 + 1]);
    }
}

extern "C" void kernel_launch(void* const* d_in, const int* in_sizes, int n_in,
                              void* d_out, int out_size, void* d_ws, size_t ws_size,
                              hipStream_t stream)
{
    const float* in_re  = (const float*)d_in[0];
    const float* in_im  = (const float*)d_in[1];
    const float* w_re   = (const float*)d_in[2];
    const float* w_im   = (const float*)d_in[3];
    const float* amp    = (const float*)d_in[4];
    const float* phase  = (const float*)d_in[5];

    uint32_t* wsA = (uint32_t*)d_ws;     // 512 KB packed bf16 A (only ws use)

    // prep also zeroes out; stream order guarantees zeroing completes
    // before gemm_direct's atomics begin.
    prep_kernel<<<dim3((NB * KC) / 256), dim3(256), 0, stream>>>(
        in_re, in_im, amp, phase, wsA, (float*)d_out);

    gemm_direct<<<dim3(NN / 32, KH), dim3(512), 0, stream>>>(
        w_re, w_im, (const bf16x8*)wsA, (float*)d_out);
}

// Round 10
// 164.160 us; speedup vs baseline: 1.2093x; 1.2093x over previous
//
#include <hip/hip_runtime.h>
#include <cstdint>
#include <cstddef>

// B=32 batch, K=4096 complex input pixels, N=4096 complex outputs.
// out[b,n] = sum_k (e_in[b,k]*ts[k]) * w[k,n]   (complex)
// Real-GEMM formulation, K'=8192 interleaved (re,im):
//   A[b][2k]=m_re, A[b][2k+1]=m_im
//   B_re[2k][n]=w_re, B_re[2k+1][n]=-w_im  -> out_re
//   B_im[2k][n]=w_im, B_im[2k+1][n]= w_re  -> out_im
// OUTPUT (established R5): float32 PLANAR — [re-plane 131072][im-plane 131072].
//
// R15 = R13 + XCD k-split swizzle (single-variable A/B).
// Ledger: delivered W-BW is a monotone function of contiguous run length
// (128B->0.87, 512B->1.75, 1KB->1.85, 2KB->1.9 TB/s) and invariant to
// depth/occupancy/barriers/glds (R5-R14) -> DRAM granule-efficiency model.
// The 16 same-k-split blocks together cover every 16KB row densely but are
// scattered 2/XCD by the default dispatch. Swizzle wgid so all 16 land on
// ONE XCD: each XCD then streams two contiguous 4MB W regions densely.
//   wgid = (s&7) + 8*(bidx + 16*(s>>3));  decode bidx=(w>>3)&15,
//   s=(w&7)+8*(w>>7). Bijective on 0..255.
#define KC 4096
#define NN 4096
#define NB 32
#define HALF (NB * NN)
#define S_SPLIT 16                       // k-splits
#define KBk 16                           // complex k per step
#define NT 256                           // n-tile per block
#define STEPS ((KC / S_SPLIT) / KBk)     // 16

typedef __attribute__((ext_vector_type(8))) short  bf16x8;  // 8 bf16 (4 VGPRs)
typedef __attribute__((ext_vector_type(16))) float f32x16;  // 32x32 MFMA acc

__device__ __forceinline__ unsigned short f2bf(float f) {
    union { float f; unsigned u; } v; v.f = f;
    unsigned r = v.u + 0x7fffu + ((v.u >> 16) & 1u);
    return (unsigned short)(r >> 16);
}

// ---------------------------------------------------------------------------
// Kernel 1 (fused prep+gemm). 1D grid 256 x 512 threads, XCD-swizzled.
//  phase A: block-local prep of this k-slice's A-octets into LDS (32 KB).
//  phase B: R9-proven gemm loop: W staged [k(16)][n(256)] x {re,im} = 32 KB
//           per step via glds (4/wave/step), double-buffered, counted
//           vmcnt(4), raw s_barriers; 4 MFMA/wave/step.
// LDS: 64 KB W + 32 KB A = 96 KB -> 1 block/CU.
// ---------------------------------------------------------------------------
__global__ __launch_bounds__(512, 2) void fused_gemm(
    const float* __restrict__ in_re, const float* __restrict__ in_im,
    const float* __restrict__ amp,   const float* __restrict__ phase,
    const float* __restrict__ w_re,  const float* __restrict__ w_im,
    float2* __restrict__ wsP)
{
    __shared__ float    ldsW[2][2][KBk][NT];   // [buf][re/im][k][n]  64 KB
    __shared__ uint32_t ldsA[8192];            // full k-slice A      32 KB

    const int tid  = threadIdx.x;
    const int lane = tid & 63;
    const int wave = tid >> 6;      // 0..7
    const int h    = lane >> 5;     // K'-octet half
    const int l32  = lane & 31;

    // XCD swizzle: all 16 n-slice blocks of one k-split share an XCD
    // (default round-robin places consecutive wgid on consecutive XCDs,
    // so wgid%8 selects the XCD; we pin wgid%8 = s%8).
    const int w    = blockIdx.x;            // 0..255
    const int bidx = (w >> 3) & 15;         // n-slice
    const int s    = (w & 7) + 8 * (w >> 7);// k-split
    const int kbase = s * (KC / S_SPLIT);   // 256-complex k-slice base

    // ---- phase A: block-local prep ------------------------------------
    // 512 threads: 2 threads per k (256 k), 16 batches each -> 8192 dwords.
    // Layout (R1-R4-established, local k): dword = ((k>>2)*32+b)*4+(k&3),
    // re lo16 / im hi16.
    {
        const int k_local = tid & 255;
        const int b0      = (tid >> 8) * 16;
        const int kg      = kbase + k_local;
        float a = amp[kg], p = phase[kg];
        float sg = 1.0f / (1.0f + __expf(-a));
        float sn = __sinf(p), cs = __cosf(p);
        float tr = sg * cs, ti = sg * sn;
#pragma unroll 4
        for (int b = b0; b < b0 + 16; ++b) {
            float er = in_re[b * KC + kg], ei = in_im[b * KC + kg];
            float mr = er * tr - ei * ti;
            float mi = er * ti + ei * tr;
            ldsA[((k_local >> 2) * 32 + b) * 4 + (k_local & 3)] =
                (uint32_t)f2bf(mr) | ((uint32_t)f2bf(mi) << 16);
        }
    }
    __syncthreads();

    // ---- phase B: gemm ------------------------------------------------
    // W staging: 32 plane-rows/step (2 planes x 16 k), 1 KB each = one glds
    // per row; 8 waves x 4 rows. glds dest = wave-uniform base + lane*16.
    const float* gW[2] = {
        w_re + (size_t)kbase * NN + bidx * NT + (lane << 2),
        w_im + (size_t)kbase * NN + bidx * NT + (lane << 2) };

    f32x16 accR = {};
    f32x16 accI = {};

    auto STAGE = [&](int t, int bb) {
#pragma unroll
        for (int i = 0; i < 4; ++i) {
            int pr    = wave * 4 + i;        // 0..31
            int plane = pr >> 4;             // 0 = re, 1 = im
            int row   = pr & 15;
            __builtin_amdgcn_global_load_lds(
                (const __attribute__((address_space(1))) void*)
                    (gW[plane] + (size_t)(t * KBk + row) * NN),
                (__attribute__((address_space(3))) void*)(&ldsW[bb][plane][row][0]),
                16, 0, 0);
        }
    };

    auto COMPUTE = [&](int t, int bb) {
#pragma unroll
        for (int ss = 0; ss < 2; ++ss) {
            // A fragment: local octet o_s = t*4 + ss*2 + h of this slice.
            const int o_s = t * 4 + ss * 2 + h;
            bf16x8 afrag = *(const bf16x8*)&ldsA[(o_s * 32 + l32) * 4];
            const float* Lre = &ldsW[bb][0][ss * 8 + h * 4][wave * 32 + l32];
            const float* Lim = &ldsW[bb][1][ss * 8 + h * 4][wave * 32 + l32];
            float r0 = Lre[0], r1 = Lre[NT], r2 = Lre[2 * NT], r3 = Lre[3 * NT];
            float i0 = Lim[0], i1 = Lim[NT], i2 = Lim[2 * NT], i3 = Lim[3 * NT];

            // f2bf(-x) == f2bf(x)^0x8000 exactly (RNE is sign-symmetric).
            unsigned short br0 = f2bf(r0), br1 = f2bf(r1), br2 = f2bf(r2), br3 = f2bf(r3);
            unsigned short bi0 = f2bf(i0), bi1 = f2bf(i1), bi2 = f2bf(i2), bi3 = f2bf(i3);
            bf16x8 bR, bI;
            bR[0] = (short)br0;  bR[1] = (short)(bi0 ^ 0x8000);
            bR[2] = (short)br1;  bR[3] = (short)(bi1 ^ 0x8000);
            bR[4] = (short)br2;  bR[5] = (short)(bi2 ^ 0x8000);
            bR[6] = (short)br3;  bR[7] = (short)(bi3 ^ 0x8000);
            bI[0] = (short)bi0;  bI[1] = (short)br0;
            bI[2] = (short)bi1;  bI[3] = (short)br1;
            bI[4] = (short)bi2;  bI[5] = (short)br2;
            bI[6] = (short)bi3;  bI[7] = (short)br3;

            accR = __builtin_amdgcn_mfma_f32_32x32x16_bf16(afrag, bR, accR, 0, 0, 0);
            accI = __builtin_amdgcn_mfma_f32_32x32x16_bf16(afrag, bI, accI, 0, 0, 0);
        }
    };

    STAGE(0, 0);
    for (int t = 0; t < STEPS - 1; ++t) {
        STAGE(t + 1, (t + 1) & 1);
        // Wait own 4 oldest (tile t); tile t+1's 4 stay in flight (m135).
        asm volatile("s_waitcnt vmcnt(4)" ::: "memory");
        __builtin_amdgcn_s_barrier();
        COMPUTE(t, t & 1);
        __builtin_amdgcn_s_barrier();
    }
    asm volatile("s_waitcnt vmcnt(0)" ::: "memory");
    __builtin_amdgcn_s_barrier();
    COMPUTE(STEPS - 1, (STEPS - 1) & 1);

    // Partials. C/D layout (32x32, verified m74/m101): col = lane&31 (=n),
    // row(batch) = (reg&3) + 8*(reg>>2) + 4*h.
    {
        const int n = bidx * NT + wave * 32 + l32;
#pragma unroll
        for (int r = 0; r < 16; ++r) {
            int brow = (r & 3) + 8 * (r >> 2) + 4 * h;
            float2 v; v.x = accR[r]; v.y = accI[r];
            wsP[((size_t)s * NB + brow) * NN + n] = v;
        }
    }
}

// ---------------------------------------------------------------------------
// Kernel 2: planar output (proven R5): out[b*4096+n]=re, out[HALF+..]=im
// float4 loads (2 complex per thread).
// ---------------------------------------------------------------------------
__global__ __launch_bounds__(256) void reduce_kernel(
    const float4* __restrict__ wsP, float* __restrict__ out)
{
    int tid = blockIdx.x * 256 + threadIdx.x;   // 65536 float4 = 2 complex
    float re0 = 0.f, im0 = 0.f, re1 = 0.f, im1 = 0.f;
#pragma unroll 8
    for (int s = 0; s < S_SPLIT; ++s) {
        float4 v = wsP[(size_t)s * (NB * NN / 2) + tid];
        re0 += v.x; im0 += v.y; re1 += v.z; im1 += v.w;
    }
    float2* o_re = (float2*)out + tid;
    float2* o_im = (float2*)(out + HALF) + tid;
    *o_re = make_float2(re0, re1);
    *o_im = make_float2(im0, im1);
}

extern "C" void kernel_launch(void* const* d_in, const int* in_sizes, int n_in,
                              void* d_out, int out_size, void* d_ws, size_t ws_size,
                              hipStream_t stream)
{
    const float* in_re  = (const float*)d_in[0];
    const float* in_im  = (const float*)d_in[1];
    const float* w_re   = (const float*)d_in[2];
    const float* w_im   = (const float*)d_in[3];
    const float* amp    = (const float*)d_in[4];
    const float* phase  = (const float*)d_in[5];

    float2* wsP = (float2*)d_ws;   // 16 MB split-K partials

    fused_gemm<<<dim3(256), dim3(512), 0, stream>>>(
        in_re, in_im, amp, phase, w_re, w_im, wsP);

    reduce_kernel<<<dim3((NB * NN / 2) / 256), dim3(256), 0, stream>>>(
        (const float4*)wsP, (float*)d_out);
}